// Round 11
// baseline (40.698 us; speedup 1.0000x reference)
//
#include <hip/hip_runtime.h>
#include <math.h>

// Problem constants (reference: B=4, N=2048, H=5, L=3)
#define B_ 4
#define N_ 2048
#define H_ 5
#define L_ 3
#define EPS_ 1e-6f

constexpr int THREADS = 256;
constexpr int WAVES = 4;
constexpr int JPT = N_ / THREADS;   // 8 elements per thread
constexpr int M_ = 17;              // Taylor terms m = 0..16
constexpr int GRID = B_ * H_;       // 20 blocks, trivially co-resident
constexpr float LOG2E = 1.4426950408889634f;

// 1/m! for m=0..16
__device__ __constant__ float INV_FACT[M_] = {
    1.0f, 1.0f, 0.5f, 1.6666666666666666e-01f, 4.1666666666666664e-02f,
    8.3333333333333332e-03f, 1.3888888888888889e-03f, 1.9841269841269841e-04f,
    2.4801587301587302e-05f, 2.7557319223985893e-06f, 2.7557319223985888e-07f,
    2.5052108385441720e-08f, 2.0876756987868100e-09f, 1.6059043836821613e-10f,
    1.1470745597729725e-11f, 7.6471637318198164e-13f, 4.7794773323873853e-14f};

// Workspace layout (floats): a[l] = 3 x [B,H,N], then 3 barrier counters
// (64-uint spaced), zeroed via hipMemsetAsync each launch.
#define WS_A(l)    (ws + (l) * (B_ * H_ * N_))
#define WS_CTR_OFF (3 * B_ * H_ * N_)
#define CTR(l)     ((unsigned*)(ws + WS_CTR_OFF) + (l) * 64)

// Device-scope counting barrier across the 20 co-resident blocks.
__device__ __forceinline__ void grid_barrier(unsigned* ctr) {
  __syncthreads();
  if (threadIdx.x == 0) {
    __threadfence();                       // release: publish a[l] writes
    atomicAdd(ctr, 1u);
    while (__hip_atomic_load(ctr, __ATOMIC_RELAXED,
                             __HIP_MEMORY_SCOPE_AGENT) < (unsigned)GRID) {
      __builtin_amdgcn_s_sleep(1);
    }
    __threadfence();                       // acquire: see others' writes
  }
  __syncthreads();
}

// Whole 3-layer encoder, ONE dispatch, 20 blocks = one per (b, head).
// Rank-1 factorized attention via Taylor separation:
//   e^{q_i k_j} = sum_m (q_i^m/m!) k_j^m
//   D_i = sum_m (q_i^m/m!) S_m,  S_m = sum_j k_j^m
//   N_i = sum_m (q_i^m/m!) T_m,  T_m = sum_j k_j^m v_j
//   att_i = (N_i - e_ii v_i)/D_i   (exact diagonal zeroing)
// Each thread owns 8 row elements; the residual lives in registers (xr)
// across all layers. Per layer: power sums -> reduce -> row phase ->
// a[l] global write -> grid barrier -> 5-head sum + LN -> xr update.
__global__ __launch_bounds__(THREADS) void fused_poly_kernel(
    const float* __restrict__ x,      // [B,N]
    const float* __restrict__ WQ,     // [L,H,N]
    const float* __restrict__ WK,     // [L,H,N]
    const float* __restrict__ WV,     // [L,H,N]
    const float* __restrict__ W0,     // [L,H]
    const float* __restrict__ gamma,  // [N]
    const float* __restrict__ beta,   // [N]
    float* __restrict__ out,          // [B,N]
    float* __restrict__ ws)
{
  __shared__ float red[WAVES][2 * M_];  // per-wave power-sum partials
  __shared__ float fin[2 * M_];         // folded S'_m, T'_m
  __shared__ float2 red2[WAVES];        // LN stat partials

  const int h = blockIdx.x % H_;
  const int b = blockIdx.x / H_;
  const int tid = threadIdx.x;
  const int wave = tid >> 6;
  const int lane = tid & 63;

  // Residual row slice + LN params in registers for the whole kernel
  float xr[JPT], gr[JPT], br[JPT];
#pragma unroll
  for (int r = 0; r < JPT; ++r) {
    const int j = tid + r * THREADS;
    xr[r] = x[b * N_ + j];
    gr[r] = gamma[j];
    br[r] = beta[j];
  }

  for (int l = 0; l < L_; ++l) {
    const float* wqh = WQ + (l * H_ + h) * N_;
    const float* wkh = WK + (l * H_ + h) * N_;
    const float* wvh = WV + (l * H_ + h) * N_;
    const float w0h = W0[l * H_ + h];
    float* a_l = WS_A(l) + (b * H_ + h) * N_;

    // ---- Power sums S_m, T_m for our head ----
    float kj[JPT], vj[JPT];
    float S[M_], T[M_];
#pragma unroll
    for (int m = 0; m < M_; ++m) { S[m] = 0.f; T[m] = 0.f; }
#pragma unroll
    for (int r = 0; r < JPT; ++r) {
      const int j = tid + r * THREADS;
      kj[r] = xr[r] * wkh[j];
      vj[r] = xr[r] * wvh[j];
      float p = 1.f;
#pragma unroll
      for (int m = 0; m < M_; ++m) {
        S[m] += p;
        T[m] = fmaf(p, vj[r], T[m]);
        p *= kj[r];
      }
    }
#pragma unroll
    for (int m = 0; m < M_; ++m) {
#pragma unroll
      for (int off = 32; off; off >>= 1) {
        S[m] += __shfl_xor(S[m], off);
        T[m] += __shfl_xor(T[m], off);
      }
      if (lane == 0) {
        red[wave][m] = S[m];
        red[wave][M_ + m] = T[m];
      }
    }
    __syncthreads();
    if (tid < 2 * M_) {
      float f = red[0][tid] + red[1][tid] + red[2][tid] + red[3][tid];
      fin[tid] = f * INV_FACT[tid < M_ ? tid : tid - M_];
    }
    __syncthreads();
    float Sf[M_], Tf[M_];
#pragma unroll
    for (int m = 0; m < M_; ++m) {
      Sf[m] = fin[m];
      Tf[m] = fin[M_ + m];
    }

    // ---- Row phase: polynomial eval, write w0-scaled per-head output ----
#pragma unroll
    for (int r = 0; r < JPT; ++r) {
      const int i = tid + r * THREADS;
      const float q = xr[r] * wqh[i];
      float d = 0.f, n = 0.f, pq = 1.f;
#pragma unroll
      for (int m = 0; m < M_; ++m) {
        d = fmaf(pq, Sf[m], d);
        n = fmaf(pq, Tf[m], n);
        pq *= q;
      }
      const float eii = __builtin_amdgcn_exp2f(q * kj[r] * LOG2E);
      a_l[i] = w0h * (n - eii * vj[r]) * __builtin_amdgcn_rcpf(d);
    }

    grid_barrier(CTR(l));

    // ---- Sum 5 heads + LN stats + residual update (redundant per b) ----
    const float* ap = WS_A(l) + b * H_ * N_;
    float aj[JPT];
    float s1 = 0.f, s2 = 0.f;
#pragma unroll
    for (int r = 0; r < JPT; ++r) {
      const int j = tid + r * THREADS;
      float v = ap[j] + ap[N_ + j] + ap[2 * N_ + j] + ap[3 * N_ + j] +
                ap[4 * N_ + j];
      aj[r] = v;
      s1 += v;
      s2 = fmaf(v, v, s2);
    }
#pragma unroll
    for (int off = 32; off; off >>= 1) {
      s1 += __shfl_xor(s1, off);
      s2 += __shfl_xor(s2, off);
    }
    if (lane == 0) red2[wave] = make_float2(s1, s2);
    __syncthreads();
    s1 = red2[0].x + red2[1].x + red2[2].x + red2[3].x;
    s2 = red2[0].y + red2[1].y + red2[2].y + red2[3].y;
    const float mean = s1 * (1.f / N_);
    const float var = (s2 - s1 * mean) * (1.f / (N_ - 1));
    const float inv = 1.f / (sqrtf(var) + EPS_);
#pragma unroll
    for (int r = 0; r < JPT; ++r) {
      xr[r] += gr[r] * (aj[r] - mean) * inv + br[r];
    }
  }

  // ---- Final output: h==0 block of each b writes the residual ----
  if (h == 0) {
#pragma unroll
    for (int r = 0; r < JPT; ++r) {
      out[b * N_ + tid + r * THREADS] = xr[r];
    }
  }
}

extern "C" void kernel_launch(void* const* d_in, const int* in_sizes, int n_in,
                              void* d_out, int out_size, void* d_ws, size_t ws_size,
                              hipStream_t stream) {
  const float* x     = (const float*)d_in[0];
  const float* WQ    = (const float*)d_in[1];
  const float* WK    = (const float*)d_in[2];
  const float* WV    = (const float*)d_in[3];
  const float* W0    = (const float*)d_in[4];
  const float* gamma = (const float*)d_in[5];
  const float* beta  = (const float*)d_in[6];
  float* out = (float*)d_out;
  float* ws  = (float*)d_ws;

  // Zero the 3 barrier counters (deterministic per launch; capture-safe)
  hipMemsetAsync((void*)CTR(0), 0, 3 * 64 * sizeof(unsigned), stream);

  fused_poly_kernel<<<GRID, THREADS, 0, stream>>>(
      x, WQ, WK, WV, W0, gamma, beta, out, ws);
}